// Round 1
// baseline (1211.979 us; speedup 1.0000x reference)
//
#include <hip/hip_runtime.h>
#include <math.h>

// Problem constants (fixed by the reference)
#define Bdim 1024
#define HdimC 256
#define OdimC 32
#define DEPTHC 6

__device__ __forceinline__ float sigmf(float x) { return 1.0f / (1.0f + expf(-x)); }

// Preorder index of node (level, q) in a full binary tree of depth DEPTHC.
// q's bits (MSB first) are the branch choices: 0 = first child, 1 = second child.
__device__ __forceinline__ int preorder_idx(int level, int q) {
    int idx = 0, rem = DEPTHC;
    for (int k = level - 1; k >= 0; --k) {
        int b = (q >> k) & 1;
        idx += 1 + b * ((1 << (rem - 1)) - 1);
        rem--;
    }
    return idx;
}

// ---------------------------------------------------------------------------
// C = A @ W^T + bias.  A: [M,256] row-major, W: [N,256] row-major.
// Output rows are remapped into a node arena: row m -> node p = m/1024,
// slot q = p*nodeStride + nodeOffset, out row = q*1024 + (m%1024).
// Tiles: 64x64, BK=32, 256 threads, 4x4 per thread, fp32.
// ---------------------------------------------------------------------------
__global__ __launch_bounds__(256) void gemm_bias_k256(
    const float* __restrict__ A, const float* __restrict__ W,
    const float* __restrict__ bias, float* __restrict__ C,
    int N, int nodeStride, int nodeOffset)
{
    __shared__ float As[32][68];
    __shared__ float Ws[32][68];

    const int tid  = threadIdx.x;
    const int row0 = blockIdx.x * 64;
    const int col0 = blockIdx.y * 64;
    const int p    = row0 >> 10;
    const int q    = p * nodeStride + nodeOffset;
    const size_t outRow0 = (size_t)q * Bdim + (row0 & 1023);

    const int lr = tid >> 3;         // 0..31 (row within tile for loads)
    const int lc = (tid & 7) * 4;    // 0..28 (k within tile for loads)
    const int r0 = (tid >> 4) * 4;   // compute rows
    const int c0 = (tid & 15) * 4;   // compute cols

    float acc[4][4] = {};

    for (int kt = 0; kt < 256; kt += 32) {
        #pragma unroll
        for (int pass = 0; pass < 2; ++pass) {
            const int rr = lr + pass * 32;
            const float4 av = *(const float4*)(A + (size_t)(row0 + rr) * 256 + kt + lc);
            const float4 wv = *(const float4*)(W + (size_t)(col0 + rr) * 256 + kt + lc);
            As[lc + 0][rr] = av.x; As[lc + 1][rr] = av.y;
            As[lc + 2][rr] = av.z; As[lc + 3][rr] = av.w;
            Ws[lc + 0][rr] = wv.x; Ws[lc + 1][rr] = wv.y;
            Ws[lc + 2][rr] = wv.z; Ws[lc + 3][rr] = wv.w;
        }
        __syncthreads();
        #pragma unroll
        for (int k = 0; k < 32; ++k) {
            const float4 a4 = *(const float4*)&As[k][r0];
            const float4 b4 = *(const float4*)&Ws[k][c0];
            const float ar[4] = {a4.x, a4.y, a4.z, a4.w};
            const float br[4] = {b4.x, b4.y, b4.z, b4.w};
            #pragma unroll
            for (int i = 0; i < 4; ++i)
                #pragma unroll
                for (int j = 0; j < 4; ++j)
                    acc[i][j] = fmaf(ar[i], br[j], acc[i][j]);
        }
        __syncthreads();
    }

    const float4 bj = *(const float4*)(bias + col0 + c0);
    #pragma unroll
    for (int i = 0; i < 4; ++i) {
        float4 v;
        v.x = acc[i][0] + bj.x; v.y = acc[i][1] + bj.y;
        v.z = acc[i][2] + bj.z; v.w = acc[i][3] + bj.w;
        *(float4*)(C + (outRow0 + r0 + i) * (size_t)N + col0 + c0) = v;
    }
}

// ---------------------------------------------------------------------------
// pred = H @ h2o_w^T + h2o_b  -> scattered to out at preorder index;
// sp = softmax(pred) -> SPbuf at node slot q.
// Block: 256 threads = 8 batch rows x 32 output cols. 128 blocks per node.
// ---------------------------------------------------------------------------
__global__ __launch_bounds__(256) void pred_softmax(
    const float* __restrict__ Hbuf, const float* __restrict__ h2o_w,
    const float* __restrict__ h2o_b, float* __restrict__ out,
    float* __restrict__ SPbuf, int level, int nodeStride, int nodeOffset)
{
    __shared__ float wsm[32][260];
    __shared__ float hsm[8][260];

    const int tid = threadIdx.x;
    const int p   = blockIdx.x >> 7;
    const int b0  = (blockIdx.x & 127) * 8;
    const int q   = p * nodeStride + nodeOffset;
    const float* Hrow = Hbuf + ((size_t)q * Bdim + b0) * HdimC;

    for (int t = tid * 4; t < 32 * 256; t += 1024) {
        const float4 v = *(const float4*)(h2o_w + t);
        const int j = t >> 8, k = t & 255;
        wsm[j][k] = v.x; wsm[j][k + 1] = v.y; wsm[j][k + 2] = v.z; wsm[j][k + 3] = v.w;
    }
    for (int t = tid * 4; t < 8 * 256; t += 1024) {
        const float4 v = *(const float4*)(Hrow + t);
        const int r = t >> 8, k = t & 255;
        hsm[r][k] = v.x; hsm[r][k + 1] = v.y; hsm[r][k + 2] = v.z; hsm[r][k + 3] = v.w;
    }
    __syncthreads();

    const int r = tid >> 5;
    const int j = tid & 31;
    float acc = 0.f;
    #pragma unroll 4
    for (int k = 0; k < 256; k += 4) {
        const float4 hv = *(const float4*)&hsm[r][k];
        const float4 wv = *(const float4*)&wsm[j][k];
        acc = fmaf(hv.x, wv.x, acc);
        acc = fmaf(hv.y, wv.y, acc);
        acc = fmaf(hv.z, wv.z, acc);
        acc = fmaf(hv.w, wv.w, acc);
    }
    acc += h2o_b[j];

    const int idx = preorder_idx(level, q);
    const int b   = b0 + r;
    out[((size_t)idx * Bdim + b) * OdimC + j] = acc;

    float mx = acc;
    #pragma unroll
    for (int off = 16; off > 0; off >>= 1) mx = fmaxf(mx, __shfl_xor(mx, off, 32));
    const float e = expf(acc - mx);
    float sum = e;
    #pragma unroll
    for (int off = 16; off > 0; off >>= 1) sum += __shfl_xor(sum, off, 32);
    SPbuf[((size_t)q * Bdim + b) * OdimC + j] = e / sum;
}

// ---------------------------------------------------------------------------
// Ancestral GRU: Apart[m,j] = (1-z)*n + z*ha[b,j]
//   r = sig(sp.wxr + bxr + GhA[b, 0:256])   (GhA = ha@wh^T + bh, per level)
//   z = sig(sp.wxz + bxz + GhA[b, 256:512])
//   n = tanh(sp.wxn + bxn + r*GhA[b, 512:768])
// Block: 16 rows x 256 cols (one col per thread).
// ---------------------------------------------------------------------------
__global__ __launch_bounds__(256) void gru_a_kernel(
    const float* __restrict__ SP, const float* __restrict__ GhA,
    const float* __restrict__ wx, const float* __restrict__ bx,
    const float* __restrict__ ha, float* __restrict__ Apart)
{
    __shared__ float sps[16][33];
    const int tid = threadIdx.x;
    const int m0  = blockIdx.x * 16;

    for (int t = tid; t < 16 * 32; t += 256)
        sps[t >> 5][t & 31] = SP[(size_t)m0 * 32 + t];
    __syncthreads();

    const int j = tid;
    float accr[16] = {}, accz[16] = {}, accn[16] = {};
    const float* wxj = wx + (size_t)j * 32;
    for (int k = 0; k < 32; ++k) {
        const float wr_ = wxj[k];
        const float wz_ = wxj[8192 + k];
        const float wn_ = wxj[16384 + k];
        #pragma unroll
        for (int r = 0; r < 16; ++r) {
            const float s = sps[r][k];
            accr[r] = fmaf(s, wr_, accr[r]);
            accz[r] = fmaf(s, wz_, accz[r]);
            accn[r] = fmaf(s, wn_, accn[r]);
        }
    }
    const float bxr = bx[j], bxz = bx[256 + j], bxn = bx[512 + j];
    #pragma unroll
    for (int r = 0; r < 16; ++r) {
        const int m = m0 + r;
        const int b = m & 1023;
        const float ghr = GhA[(size_t)b * 768 + j];
        const float ghz = GhA[(size_t)b * 768 + 256 + j];
        const float ghn = GhA[(size_t)b * 768 + 512 + j];
        const float rg = sigmf(accr[r] + bxr + ghr);
        const float zg = sigmf(accz[r] + bxz + ghz);
        const float ng = tanhf(accn[r] + bxn + rg * ghn);
        Apart[(size_t)m * 256 + j] = (1.f - zg) * ng + zg * ha[(size_t)b * 256 + j];
    }
}

// ---------------------------------------------------------------------------
// Fraternal GRU fused GEMM + combine, then hidden2 = gru_s_out + Apart (in place).
//   h = Hnext slots 2p (first children), x = SPnext slots 2p.
//   3 accumulators per output (r,z,n h-parts), K=256; x-parts (K=32) in epilogue.
// ---------------------------------------------------------------------------
__global__ __launch_bounds__(256) void gru_s_gemm(
    const float* __restrict__ Hnext, const float* __restrict__ SPnext,
    const float* __restrict__ wh, const float* __restrict__ bh,
    const float* __restrict__ wx, const float* __restrict__ bx,
    float* __restrict__ Apart)
{
    __shared__ float Hs[32][68];
    __shared__ float Wr[32][68];
    __shared__ float Wz[32][68];
    __shared__ float Wn[32][68];
    __shared__ float sps[64][33];

    const int tid  = threadIdx.x;
    const int m0   = blockIdx.x * 64;
    const int col0 = blockIdx.y * 64;
    const int p    = m0 >> 10;
    const float* hstBase = Hnext  + ((size_t)(2 * p) * Bdim + (m0 & 1023)) * 256;
    const float* spBase  = SPnext + ((size_t)(2 * p) * Bdim + (m0 & 1023)) * 32;

    const int lr = tid >> 3;
    const int lc = (tid & 7) * 4;
    const int r0 = (tid >> 4) * 4;
    const int c0 = (tid & 15) * 4;

    float accr[4][4] = {}, accz[4][4] = {}, accn[4][4] = {};

    for (int kt = 0; kt < 256; kt += 32) {
        #pragma unroll
        for (int pass = 0; pass < 2; ++pass) {
            const int rr = lr + pass * 32;
            const float4 hv = *(const float4*)(hstBase + (size_t)rr * 256 + kt + lc);
            const float4 w0 = *(const float4*)(wh +          (size_t)(col0 + rr) * 256 + kt + lc);
            const float4 w1 = *(const float4*)(wh + 65536  + (size_t)(col0 + rr) * 256 + kt + lc);
            const float4 w2 = *(const float4*)(wh + 131072 + (size_t)(col0 + rr) * 256 + kt + lc);
            Hs[lc + 0][rr] = hv.x; Hs[lc + 1][rr] = hv.y; Hs[lc + 2][rr] = hv.z; Hs[lc + 3][rr] = hv.w;
            Wr[lc + 0][rr] = w0.x; Wr[lc + 1][rr] = w0.y; Wr[lc + 2][rr] = w0.z; Wr[lc + 3][rr] = w0.w;
            Wz[lc + 0][rr] = w1.x; Wz[lc + 1][rr] = w1.y; Wz[lc + 2][rr] = w1.z; Wz[lc + 3][rr] = w1.w;
            Wn[lc + 0][rr] = w2.x; Wn[lc + 1][rr] = w2.y; Wn[lc + 2][rr] = w2.z; Wn[lc + 3][rr] = w2.w;
        }
        __syncthreads();
        #pragma unroll
        for (int k = 0; k < 32; ++k) {
            const float4 a4 = *(const float4*)&Hs[k][r0];
            const float4 r4 = *(const float4*)&Wr[k][c0];
            const float4 z4 = *(const float4*)&Wz[k][c0];
            const float4 n4 = *(const float4*)&Wn[k][c0];
            const float ar[4] = {a4.x, a4.y, a4.z, a4.w};
            const float rr_[4] = {r4.x, r4.y, r4.z, r4.w};
            const float zz_[4] = {z4.x, z4.y, z4.z, z4.w};
            const float nn_[4] = {n4.x, n4.y, n4.z, n4.w};
            #pragma unroll
            for (int i = 0; i < 4; ++i)
                #pragma unroll
                for (int j = 0; j < 4; ++j) {
                    accr[i][j] = fmaf(ar[i], rr_[j], accr[i][j]);
                    accz[i][j] = fmaf(ar[i], zz_[j], accz[i][j]);
                    accn[i][j] = fmaf(ar[i], nn_[j], accn[i][j]);
                }
        }
        __syncthreads();
    }

    for (int t = tid * 4; t < 64 * 32; t += 1024) {
        const float4 v = *(const float4*)(spBase + t);
        const int rr = t >> 5, kk = t & 31;
        sps[rr][kk] = v.x; sps[rr][kk + 1] = v.y; sps[rr][kk + 2] = v.z; sps[rr][kk + 3] = v.w;
    }
    __syncthreads();

    float xn[4][4] = {};
    #pragma unroll
    for (int jj = 0; jj < 4; ++jj) {
        const int jc = col0 + c0 + jj;
        const float* wxj = wx + (size_t)jc * 32;
        for (int k = 0; k < 32; ++k) {
            const float wr_ = wxj[k];
            const float wz_ = wxj[8192 + k];
            const float wn_ = wxj[16384 + k];
            #pragma unroll
            for (int i = 0; i < 4; ++i) {
                const float s = sps[r0 + i][k];
                accr[i][jj] = fmaf(s, wr_, accr[i][jj]);
                accz[i][jj] = fmaf(s, wz_, accz[i][jj]);
                xn[i][jj]   = fmaf(s, wn_, xn[i][jj]);
            }
        }
    }

    #pragma unroll
    for (int i = 0; i < 4; ++i) {
        #pragma unroll
        for (int jj = 0; jj < 4; ++jj) {
            const int jc = col0 + c0 + jj;
            const float rg = sigmf(accr[i][jj] + bx[jc] + bh[jc]);
            const float zg = sigmf(accz[i][jj] + bx[256 + jc] + bh[256 + jc]);
            const float ng = tanhf(xn[i][jj] + bx[512 + jc] + rg * (accn[i][jj] + bh[512 + jc]));
            const float hv = hstBase[(size_t)(r0 + i) * 256 + jc];
            const size_t mrow = (size_t)(m0 + r0 + i);
            Apart[mrow * 256 + jc] += (1.f - zg) * ng + zg * hv;
        }
    }
}

// ---------------------------------------------------------------------------
extern "C" void kernel_launch(void* const* d_in, const int* in_sizes, int n_in,
                              void* d_out, int out_size, void* d_ws, size_t ws_size,
                              hipStream_t stream) {
    (void)in_sizes; (void)n_in; (void)out_size; (void)ws_size;

    const float* z      = (const float*)d_in[0];
    const float* h2o_w  = (const float*)d_in[1];
    const float* h2o_b  = (const float*)d_in[2];
    const float* w_c_w  = (const float*)d_in[3];
    const float* w_c_b  = (const float*)d_in[4];
    const float* w_d_w  = (const float*)d_in[5];
    const float* w_d_b  = (const float*)d_in[6];
    const float* z2h1_w = (const float*)d_in[7];
    const float* z2h1_b = (const float*)d_in[8];
    const float* z2h2_w = (const float*)d_in[9];
    const float* z2h2_b = (const float*)d_in[10];
    const float* ga_wx  = (const float*)d_in[11];
    const float* ga_wh  = (const float*)d_in[12];
    const float* ga_bx  = (const float*)d_in[13];
    const float* ga_bh  = (const float*)d_in[14];
    const float* gs_wx  = (const float*)d_in[15];
    const float* gs_wh  = (const float*)d_in[16];
    const float* gs_bx  = (const float*)d_in[17];
    const float* gs_bh  = (const float*)d_in[18];

    float* out = (float*)d_out;
    float* ws  = (float*)d_ws;

    // Workspace layout (floats): needs ~97.5 MB total.
    const size_t HN = (size_t)32 * Bdim * HdimC;   // 8,388,608
    const size_t SN = (size_t)32 * Bdim * OdimC;   // 1,048,576
    float* H0  = ws;
    float* H1  = H0 + HN;
    float* SP0 = H1 + HN;
    float* SP1 = SP0 + SN;
    float* HA0 = SP1 + SN;
    float* HA1 = HA0 + (size_t)Bdim * HdimC;
    float* GhA = HA1 + (size_t)Bdim * HdimC;
    float* Ap  = GhA + (size_t)Bdim * 768;

    const dim3 blk(256);

    // Init: HA_0 = z@z2h1^T+b ; H_0 = z@z2h2^T+b ; root pred+softmax
    gemm_bias_k256<<<dim3(Bdim / 64, 4), blk, 0, stream>>>(z, z2h1_w, z2h1_b, HA0, 256, 1, 0);
    gemm_bias_k256<<<dim3(Bdim / 64, 4), blk, 0, stream>>>(z, z2h2_w, z2h2_b, H0, 256, 1, 0);
    pred_softmax<<<dim3(Bdim / 8), blk, 0, stream>>>(H0, h2o_w, h2o_b, out, SP0, 0, 1, 0);

    float* Hc = H0;  float* Hn = H1;
    float* SPc = SP0; float* SPn = SP1;
    float* hac = HA0; float* han = HA1;

    for (int l = 0; l < DEPTHC - 1; ++l) {
        const int n = 1 << l;
        const int M = n * Bdim;

        // First children: H1 = lin_d(Hc) -> slots 2p
        gemm_bias_k256<<<dim3(M / 64, 4), blk, 0, stream>>>(Hc, w_d_w, w_d_b, Hn, 256, 2, 0);
        // pred + softmax of first children (level l+1, slots 2p)
        pred_softmax<<<dim3(M / 8), blk, 0, stream>>>(Hn, h2o_w, h2o_b, out, SPn, l + 1, 2, 0);
        // Shared ancestral gate h-part: GhA = hac @ ga_wh^T + ga_bh  [1024 x 768]
        gemm_bias_k256<<<dim3(Bdim / 64, 12), blk, 0, stream>>>(hac, ga_wh, ga_bh, GhA, 768, 1, 0);
        // Ancestral GRU (per-node x-part): Ap = gru_a(SPc, hac)
        gru_a_kernel<<<dim3(M / 16), blk, 0, stream>>>(SPc, GhA, ga_wx, ga_bx, hac, Ap);
        // Fraternal GRU on first children, hidden2 = gru_s + Ap (in place)
        gru_s_gemm<<<dim3(M / 64, 4), blk, 0, stream>>>(Hn, SPn, gs_wh, gs_bh, gs_wx, gs_bx, Ap);
        // Second children: H2 = lin_d(hidden2) -> slots 2p+1
        gemm_bias_k256<<<dim3(M / 64, 4), blk, 0, stream>>>(Ap, w_d_w, w_d_b, Hn, 256, 2, 1);
        // pred + softmax of second children
        pred_softmax<<<dim3(M / 8), blk, 0, stream>>>(Hn, h2o_w, h2o_b, out, SPn, l + 1, 2, 1);
        // Next level shared ancestral hidden: HA' = lin_c(hac)
        gemm_bias_k256<<<dim3(Bdim / 64, 4), blk, 0, stream>>>(hac, w_c_w, w_c_b, han, 256, 1, 0);

        // swap ping-pong buffers
        float* t;
        t = Hc;  Hc = Hn;  Hn = t;
        t = SPc; SPc = SPn; SPn = t;
        t = hac; hac = han; han = t;
    }
}

// Round 2
// 822.633 us; speedup vs baseline: 1.4733x; 1.4733x over previous
//
#include <hip/hip_runtime.h>
#include <math.h>

// Problem constants (fixed by the reference)
#define Bdim 1024
#define HdimC 256
#define OdimC 32
#define DEPTHC 6

typedef __attribute__((ext_vector_type(8))) short bf16x8;
typedef __attribute__((ext_vector_type(4))) float f32x4;

__device__ __forceinline__ unsigned short f2bf(float x) {
    unsigned u = __float_as_uint(x);
    u += 0x7fffu + ((u >> 16) & 1u);
    return (unsigned short)(u >> 16);
}
__device__ __forceinline__ float bf2f(unsigned short h) {
    return __uint_as_float(((unsigned)h) << 16);
}
__device__ __forceinline__ float sigmf(float x) { return 1.0f / (1.0f + expf(-x)); }

__device__ __forceinline__ void glds16(const void* g, void* l) {
    __builtin_amdgcn_global_load_lds(
        (const __attribute__((address_space(1))) unsigned int*)g,
        (__attribute__((address_space(3))) unsigned int*)l, 16, 0, 0);
}

// Preorder index of node (level, q) in a full binary tree of depth DEPTHC.
__device__ __forceinline__ int preorder_idx(int level, int q) {
    int idx = 0, rem = DEPTHC;
    for (int k = level - 1; k >= 0; --k) {
        int b = (q >> k) & 1;
        idx += 1 + b * ((1 << (rem - 1)) - 1);
        rem--;
    }
    return idx;
}

// ---------------------------------------------------------------------------
// fp32 -> bf16x2 split converter: dst[r][0:k]=hi, dst[r][k:2k]=lo
// ---------------------------------------------------------------------------
struct CvtEnt { const float* src; unsigned short* dst; int n; int klog2; };
struct CvtArgs { CvtEnt e[8]; };

__global__ __launch_bounds__(256) void cvt_bf16x2(CvtArgs a) {
    CvtEnt E = a.e[blockIdx.y];
    const int k = 1 << E.klog2;
    for (int t = blockIdx.x * 256 + threadIdx.x; t < E.n; t += gridDim.x * 256) {
        const float x = E.src[t];
        const int r = t >> E.klog2, c = t & (k - 1);
        const unsigned short hi = f2bf(x);
        unsigned short* d = E.dst + ((size_t)r << (E.klog2 + 1));
        d[c] = hi;
        d[k + c] = f2bf(x - bf2f(hi));
    }
}

// ---------------------------------------------------------------------------
// Generic bf16x2 MFMA GEMM: C = A @ W^T + bias, logical K=256, stored K=512
// (hi|lo). 12-step schedule covers hi*hi, lo*hi, hi*lo products (K_eff=768).
// A: contiguous [M,512]. W2: [N,512]. Tile 128x128, BK=64, 4 waves (2x2).
// Output row m -> node p=m>>10, out row = (p*outStride+outOffset)*1024+(m&1023).
// Cf (fp32, row stride N) and/or C2 (bf16x2, [*,512]) may be null.
// ---------------------------------------------------------------------------
__global__ __launch_bounds__(256) void mfma_gemm(
    const unsigned short* __restrict__ A2, const unsigned short* __restrict__ W2,
    const float* __restrict__ bias, float* __restrict__ Cf,
    unsigned short* __restrict__ C2, int N, int outStride, int outOffset)
{
    __shared__ __attribute__((aligned(16))) unsigned short As[8192];
    __shared__ __attribute__((aligned(16))) unsigned short Ws[8192];

    const int tid = threadIdx.x;
    const int w = tid >> 6, lane = tid & 63;
    const int m0 = blockIdx.x * 128, col0 = blockIdx.y * 128;
    const int p = m0 >> 10;

    const int srow = (w << 5) + (lane >> 3);  // + i*8
    const int sslot = lane & 7;
    const int wm = (w >> 1) << 6, wn = (w & 1) << 6;

    f32x4 acc[4][4];
    #pragma unroll
    for (int i = 0; i < 4; ++i)
        #pragma unroll
        for (int j = 0; j < 4; ++j)
            #pragma unroll
            for (int r = 0; r < 4; ++r) acc[i][j][r] = 0.f;

    for (int s = 0; s < 12; ++s) {
        const int ka = ((s & 3) << 6) + (((unsigned)(s - 4) < 4u) ? 256 : 0);
        const int kw = ((s & 3) << 6) + ((s >= 8) ? 256 : 0);
        #pragma unroll
        for (int i = 0; i < 4; ++i) {
            const int r = srow + (i << 3);
            const int sl = sslot ^ (r & 7);
            glds16(A2 + (size_t)(m0 + r) * 512 + ka + (sl << 3),
                   &As[(w << 11) + (i << 9)]);
            glds16(W2 + (size_t)(col0 + r) * 512 + kw + (sl << 3),
                   &Ws[(w << 11) + (i << 9)]);
        }
        __syncthreads();
        #pragma unroll
        for (int kk = 0; kk < 2; ++kk) {
            bf16x8 af[4], bw[4];
            #pragma unroll
            for (int mf = 0; mf < 4; ++mf) {
                const int row = wm + (mf << 4) + (lane & 15);
                const int sl = (((kk << 2) | (lane >> 4)) ^ (row & 7)) << 3;
                af[mf] = *(const bf16x8*)&As[(row << 6) + sl];
            }
            #pragma unroll
            for (int nf = 0; nf < 4; ++nf) {
                const int row = wn + (nf << 4) + (lane & 15);
                const int sl = (((kk << 2) | (lane >> 4)) ^ (row & 7)) << 3;
                bw[nf] = *(const bf16x8*)&Ws[(row << 6) + sl];
            }
            #pragma unroll
            for (int mf = 0; mf < 4; ++mf)
                #pragma unroll
                for (int nf = 0; nf < 4; ++nf)
                    acc[mf][nf] = __builtin_amdgcn_mfma_f32_16x16x32_bf16(
                        af[mf], bw[nf], acc[mf][nf], 0, 0, 0);
        }
        __syncthreads();
    }

    const size_t oBase = (((size_t)(p * outStride + outOffset)) << 10) + (m0 & 1023);
    #pragma unroll
    for (int nf = 0; nf < 4; ++nf) {
        const int col = col0 + wn + (nf << 4) + (lane & 15);
        const float bj = bias[col];
        #pragma unroll
        for (int mf = 0; mf < 4; ++mf) {
            const int rb = wm + (mf << 4) + ((lane >> 4) << 2);
            #pragma unroll
            for (int r = 0; r < 4; ++r) {
                const float v = acc[mf][nf][r] + bj;
                const size_t orow = oBase + rb + r;
                if (Cf) Cf[orow * (size_t)N + col] = v;
                if (C2) {
                    const unsigned short hi = f2bf(v);
                    C2[orow * 512 + col] = hi;
                    C2[orow * 512 + 256 + col] = f2bf(v - bf2f(hi));
                }
            }
        }
    }
}

// ---------------------------------------------------------------------------
// pred = H @ h2o_w^T + h2o_b -> scatter to out at preorder index;
// sp = softmax(pred) -> SP2 (bf16x2, [slot][1024][64]).
// H read from bf16x2 arena (hi+lo reconstruct). 256 thr = 8 rows x 32 cols.
// ---------------------------------------------------------------------------
__global__ __launch_bounds__(256) void pred_softmax(
    const unsigned short* __restrict__ H2, const float* __restrict__ h2o_w,
    const float* __restrict__ h2o_b, float* __restrict__ out,
    unsigned short* __restrict__ SP2, int level, int nodeStride, int nodeOffset)
{
    __shared__ float wsm[32][260];
    __shared__ float hsm[8][260];

    const int tid = threadIdx.x;
    const int p   = blockIdx.x >> 7;
    const int b0  = (blockIdx.x & 127) * 8;
    const int q   = p * nodeStride + nodeOffset;
    const unsigned short* Hrow = H2 + ((size_t)q * Bdim + b0) * 512;

    for (int t = tid * 4; t < 32 * 256; t += 1024) {
        const float4 v = *(const float4*)(h2o_w + t);
        const int j = t >> 8, k = t & 255;
        wsm[j][k] = v.x; wsm[j][k + 1] = v.y; wsm[j][k + 2] = v.z; wsm[j][k + 3] = v.w;
    }
    for (int t = tid * 4; t < 8 * 256; t += 1024) {
        const int r = t >> 8, k = t & 255;
        const ushort4 hi4 = *(const ushort4*)(Hrow + (size_t)r * 512 + k);
        const ushort4 lo4 = *(const ushort4*)(Hrow + (size_t)r * 512 + 256 + k);
        hsm[r][k + 0] = bf2f(hi4.x) + bf2f(lo4.x);
        hsm[r][k + 1] = bf2f(hi4.y) + bf2f(lo4.y);
        hsm[r][k + 2] = bf2f(hi4.z) + bf2f(lo4.z);
        hsm[r][k + 3] = bf2f(hi4.w) + bf2f(lo4.w);
    }
    __syncthreads();

    const int r = tid >> 5;
    const int j = tid & 31;
    float acc = 0.f;
    #pragma unroll 4
    for (int k = 0; k < 256; k += 4) {
        const float4 hv = *(const float4*)&hsm[r][k];
        const float4 wv = *(const float4*)&wsm[j][k];
        acc = fmaf(hv.x, wv.x, acc);
        acc = fmaf(hv.y, wv.y, acc);
        acc = fmaf(hv.z, wv.z, acc);
        acc = fmaf(hv.w, wv.w, acc);
    }
    acc += h2o_b[j];

    const int idx = preorder_idx(level, q);
    const int b   = b0 + r;
    out[((size_t)idx * Bdim + b) * OdimC + j] = acc;

    float mx = acc;
    #pragma unroll
    for (int off = 16; off > 0; off >>= 1) mx = fmaxf(mx, __shfl_xor(mx, off, 32));
    const float e = expf(acc - mx);
    float sum = e;
    #pragma unroll
    for (int off = 16; off > 0; off >>= 1) sum += __shfl_xor(sum, off, 32);
    const float sp = e / sum;

    const size_t sbase = ((size_t)q * Bdim + b) * 64;
    const unsigned short hi = f2bf(sp);
    SP2[sbase + j] = hi;
    SP2[sbase + 32 + j] = f2bf(sp - bf2f(hi));
}

// ---------------------------------------------------------------------------
// Ancestral GRU (per-node x-part + shared h-part GhA): Ap[m,j] = (1-z)*n + z*ha
// SP2c: parents' softmax (bf16x2). 16 rows x 256 cols per block.
// ---------------------------------------------------------------------------
__global__ __launch_bounds__(256) void gru_a_kernel(
    const unsigned short* __restrict__ SP2c, const float* __restrict__ GhA,
    const float* __restrict__ wx, const float* __restrict__ bx,
    const float* __restrict__ ha, float* __restrict__ Apart)
{
    __shared__ float sps[16][33];
    const int tid = threadIdx.x;
    const int m0  = blockIdx.x * 16;

    for (int t = tid; t < 16 * 32; t += 256) {
        const int r = t >> 5, k = t & 31;
        const size_t base = ((size_t)(m0 + r)) * 64;
        sps[r][k] = bf2f(SP2c[base + k]) + bf2f(SP2c[base + 32 + k]);
    }
    __syncthreads();

    const int j = tid;
    float accr[16] = {}, accz[16] = {}, accn[16] = {};
    const float* wxj = wx + (size_t)j * 32;
    for (int k = 0; k < 32; ++k) {
        const float wr_ = wxj[k];
        const float wz_ = wxj[8192 + k];
        const float wn_ = wxj[16384 + k];
        #pragma unroll
        for (int r = 0; r < 16; ++r) {
            const float s = sps[r][k];
            accr[r] = fmaf(s, wr_, accr[r]);
            accz[r] = fmaf(s, wz_, accz[r]);
            accn[r] = fmaf(s, wn_, accn[r]);
        }
    }
    const float bxr = bx[j], bxz = bx[256 + j], bxn = bx[512 + j];
    #pragma unroll
    for (int r = 0; r < 16; ++r) {
        const int m = m0 + r;
        const int b = m & 1023;
        const float ghr = GhA[(size_t)b * 768 + j];
        const float ghz = GhA[(size_t)b * 768 + 256 + j];
        const float ghn = GhA[(size_t)b * 768 + 512 + j];
        const float rg = sigmf(accr[r] + bxr + ghr);
        const float zg = sigmf(accz[r] + bxz + ghz);
        const float ng = tanhf(accn[r] + bxn + rg * ghn);
        Apart[(size_t)m * 256 + j] = (1.f - zg) * ng + zg * ha[(size_t)b * 256 + j];
    }
}

// ---------------------------------------------------------------------------
// Fraternal GRU fused MFMA: h = first-child hidden (bf16x2, slots 2p),
// x = first-child softmax (SP2, slots 2p). 3 gates on a 64-col slab.
// 12 h-steps (K_eff=768) + 1 x-step (K=64). Epilogue: gates + add Ap (gru_a),
// write hidden2 as bf16x2 into Ap2.
// ---------------------------------------------------------------------------
__global__ __launch_bounds__(256) void gru_s_fused(
    const unsigned short* __restrict__ Hn2, const unsigned short* __restrict__ SP2n,
    const unsigned short* __restrict__ whW2, const unsigned short* __restrict__ wxW2,
    const float* __restrict__ bx, const float* __restrict__ bh,
    const float* __restrict__ Apf, unsigned short* __restrict__ Ap2)
{
    __shared__ __attribute__((aligned(16))) unsigned short As[8192];    // 128x64
    __shared__ __attribute__((aligned(16))) unsigned short Ws[12288];   // 3x64x64

    const int tid = threadIdx.x;
    const int w = tid >> 6, lane = tid & 63;
    const int m0 = blockIdx.x * 128;
    const int col0 = blockIdx.y * 64;
    const int p = m0 >> 10;
    const size_t aBase = (((size_t)(2 * p)) << 10) + (m0 & 1023);

    const int srow = (w << 5) + (lane >> 3);
    const int sslot = lane & 7;
    const int wm = (w >> 1) << 6;   // row offset 0/64
    const int wn = (w & 1) << 5;    // col offset 0/32

    f32x4 accg[3][4][2];
    f32x4 accnx[4][2];
    #pragma unroll
    for (int g = 0; g < 3; ++g)
        #pragma unroll
        for (int i = 0; i < 4; ++i)
            #pragma unroll
            for (int j = 0; j < 2; ++j)
                #pragma unroll
                for (int r = 0; r < 4; ++r) accg[g][i][j][r] = 0.f;
    #pragma unroll
    for (int i = 0; i < 4; ++i)
        #pragma unroll
        for (int j = 0; j < 2; ++j)
            #pragma unroll
            for (int r = 0; r < 4; ++r) accnx[i][j][r] = 0.f;

    // --- main h-path: 12 steps over bf16x2 split products ---
    for (int s = 0; s < 12; ++s) {
        const int ka = ((s & 3) << 6) + (((unsigned)(s - 4) < 4u) ? 256 : 0);
        const int kw = ((s & 3) << 6) + ((s >= 8) ? 256 : 0);
        #pragma unroll
        for (int i = 0; i < 4; ++i) {
            const int r = srow + (i << 3);
            const int sl = sslot ^ (r & 7);
            glds16(Hn2 + (aBase + r) * 512 + ka + (sl << 3), &As[(w << 11) + (i << 9)]);
        }
        #pragma unroll
        for (int j = 0; j < 6; ++j) {
            const int R = w * 48 + j * 8 + (lane >> 3);
            const int g = R >> 6, rr = R & 63;
            const int sl = sslot ^ (rr & 7);
            glds16(whW2 + (size_t)(g * 256 + col0 + rr) * 512 + kw + (sl << 3),
                   &Ws[(w * 48 + j * 8) * 64]);
        }
        __syncthreads();
        #pragma unroll
        for (int kk = 0; kk < 2; ++kk) {
            bf16x8 af[4], bg[3][2];
            #pragma unroll
            for (int mf = 0; mf < 4; ++mf) {
                const int row = wm + (mf << 4) + (lane & 15);
                const int sl = (((kk << 2) | (lane >> 4)) ^ (row & 7)) << 3;
                af[mf] = *(const bf16x8*)&As[(row << 6) + sl];
            }
            #pragma unroll
            for (int g = 0; g < 3; ++g)
                #pragma unroll
                for (int nf = 0; nf < 2; ++nf) {
                    const int R = (g << 6) + wn + (nf << 4) + (lane & 15);
                    const int sl = (((kk << 2) | (lane >> 4)) ^ (R & 7)) << 3;
                    bg[g][nf] = *(const bf16x8*)&Ws[(R << 6) + sl];
                }
            #pragma unroll
            for (int mf = 0; mf < 4; ++mf)
                #pragma unroll
                for (int nf = 0; nf < 2; ++nf) {
                    accg[0][mf][nf] = __builtin_amdgcn_mfma_f32_16x16x32_bf16(af[mf], bg[0][nf], accg[0][mf][nf], 0, 0, 0);
                    accg[1][mf][nf] = __builtin_amdgcn_mfma_f32_16x16x32_bf16(af[mf], bg[1][nf], accg[1][mf][nf], 0, 0, 0);
                    accg[2][mf][nf] = __builtin_amdgcn_mfma_f32_16x16x32_bf16(af[mf], bg[2][nf], accg[2][mf][nf], 0, 0, 0);
                }
        }
        __syncthreads();
    }

    // --- x-path: one K=64 step (SP2 hi|lo vs wx2 hi|lo) ---
    #pragma unroll
    for (int i = 0; i < 4; ++i) {
        const int r = srow + (i << 3);
        const int sl = sslot ^ (r & 7);
        glds16(SP2n + (aBase + r) * 64 + (sl << 3), &As[(w << 11) + (i << 9)]);
    }
    #pragma unroll
    for (int j = 0; j < 6; ++j) {
        const int R = w * 48 + j * 8 + (lane >> 3);
        const int g = R >> 6, rr = R & 63;
        const int sl = sslot ^ (rr & 7);
        glds16(wxW2 + (size_t)(g * 256 + col0 + rr) * 64 + (sl << 3),
               &Ws[(w * 48 + j * 8) * 64]);
    }
    __syncthreads();
    #pragma unroll
    for (int kk = 0; kk < 2; ++kk) {
        bf16x8 af[4], bg[3][2];
        #pragma unroll
        for (int mf = 0; mf < 4; ++mf) {
            const int row = wm + (mf << 4) + (lane & 15);
            const int sl = (((kk << 2) | (lane >> 4)) ^ (row & 7)) << 3;
            af[mf] = *(const bf16x8*)&As[(row << 6) + sl];
        }
        #pragma unroll
        for (int g = 0; g < 3; ++g)
            #pragma unroll
            for (int nf = 0; nf < 2; ++nf) {
                const int R = (g << 6) + wn + (nf << 4) + (lane & 15);
                const int sl = (((kk << 2) | (lane >> 4)) ^ (R & 7)) << 3;
                bg[g][nf] = *(const bf16x8*)&Ws[(R << 6) + sl];
            }
        #pragma unroll
        for (int mf = 0; mf < 4; ++mf)
            #pragma unroll
            for (int nf = 0; nf < 2; ++nf) {
                accg[0][mf][nf] = __builtin_amdgcn_mfma_f32_16x16x32_bf16(af[mf], bg[0][nf], accg[0][mf][nf], 0, 0, 0);
                accg[1][mf][nf] = __builtin_amdgcn_mfma_f32_16x16x32_bf16(af[mf], bg[1][nf], accg[1][mf][nf], 0, 0, 0);
                accnx[mf][nf]   = __builtin_amdgcn_mfma_f32_16x16x32_bf16(af[mf], bg[2][nf], accnx[mf][nf], 0, 0, 0);
            }
    }

    // --- epilogue: gates, combine with gru_a part, write bf16x2 hidden2 ---
    #pragma unroll
    for (int nf = 0; nf < 2; ++nf) {
        const int jc = col0 + wn + (nf << 4) + (lane & 15);
        const float brz = bx[jc] + bh[jc];
        const float bzz = bx[256 + jc] + bh[256 + jc];
        const float bxn = bx[512 + jc];
        const float bhn = bh[512 + jc];
        #pragma unroll
        for (int mf = 0; mf < 4; ++mf) {
            #pragma unroll
            for (int r = 0; r < 4; ++r) {
                const int rowl = wm + (mf << 4) + ((lane >> 4) << 2) + r;
                const float rg = sigmf(accg[0][mf][nf][r] + brz);
                const float zg = sigmf(accg[1][mf][nf][r] + bzz);
                const float ng = tanhf(accnx[mf][nf][r] + bxn + rg * (accg[2][mf][nf][r] + bhn));
                const size_t hrow = aBase + rowl;
                const float hv = bf2f(Hn2[hrow * 512 + jc]) + bf2f(Hn2[hrow * 512 + 256 + jc]);
                const size_t m = (size_t)(m0 + rowl);
                const float val = (1.f - zg) * ng + zg * hv + Apf[m * 256 + jc];
                const unsigned short hi = f2bf(val);
                Ap2[m * 512 + jc] = hi;
                Ap2[m * 512 + 256 + jc] = f2bf(val - bf2f(hi));
            }
        }
    }
}

// ---------------------------------------------------------------------------
extern "C" void kernel_launch(void* const* d_in, const int* in_sizes, int n_in,
                              void* d_out, int out_size, void* d_ws, size_t ws_size,
                              hipStream_t stream) {
    (void)in_sizes; (void)n_in; (void)out_size;

    const float* z      = (const float*)d_in[0];
    const float* h2o_w  = (const float*)d_in[1];
    const float* h2o_b  = (const float*)d_in[2];
    const float* w_c_w  = (const float*)d_in[3];
    const float* w_c_b  = (const float*)d_in[4];
    const float* w_d_w  = (const float*)d_in[5];
    const float* w_d_b  = (const float*)d_in[6];
    const float* z2h1_w = (const float*)d_in[7];
    const float* z2h1_b = (const float*)d_in[8];
    const float* z2h2_w = (const float*)d_in[9];
    const float* z2h2_b = (const float*)d_in[10];
    const float* ga_wx  = (const float*)d_in[11];
    const float* ga_wh  = (const float*)d_in[12];
    const float* ga_bx  = (const float*)d_in[13];
    const float* ga_bh  = (const float*)d_in[14];
    const float* gs_wx  = (const float*)d_in[15];
    const float* gs_wh  = (const float*)d_in[16];
    const float* gs_bx  = (const float*)d_in[17];
    const float* gs_bh  = (const float*)d_in[18];

    float* out = (float*)d_out;

    // bump allocator over d_ws (~96.6 MB total)
    size_t off = 0;
    auto alloc = [&](size_t bytes) -> void* {
        void* r = (char*)d_ws + off;
        off += (bytes + 255) & ~(size_t)255;
        return r;
    };
    unsigned short* H2a  = (unsigned short*)alloc(16ull * 1024 * 512 * 2); // 16 slots
    unsigned short* H2b  = (unsigned short*)alloc(32ull * 1024 * 512 * 2); // 32 slots
    unsigned short* SP2a = (unsigned short*)alloc(16ull * 1024 * 64 * 2);
    unsigned short* SP2b = (unsigned short*)alloc(32ull * 1024 * 64 * 2);
    float* hacF0 = (float*)alloc(1024ull * 256 * 4);
    float* hacF1 = (float*)alloc(1024ull * 256 * 4);
    unsigned short* hac20 = (unsigned short*)alloc(1024ull * 512 * 2);
    unsigned short* hac21 = (unsigned short*)alloc(1024ull * 512 * 2);
    float* GhA = (float*)alloc(1024ull * 768 * 4);
    float* Ap  = (float*)alloc(16ull * 1024 * 256 * 4);
    unsigned short* Ap2 = (unsigned short*)alloc(16ull * 1024 * 512 * 2);
    unsigned short* z2  = (unsigned short*)alloc(1024ull * 512 * 2);
    unsigned short* wd2 = (unsigned short*)alloc(256ull * 512 * 2);
    unsigned short* wc2 = (unsigned short*)alloc(256ull * 512 * 2);
    unsigned short* z12 = (unsigned short*)alloc(256ull * 512 * 2);
    unsigned short* z22 = (unsigned short*)alloc(256ull * 512 * 2);
    unsigned short* gaW2 = (unsigned short*)alloc(768ull * 512 * 2);
    unsigned short* gsW2 = (unsigned short*)alloc(768ull * 512 * 2);
    unsigned short* gsX2 = (unsigned short*)alloc(768ull * 64 * 2);
    if (off > ws_size) return;  // tripwire: output stays zero -> visible fail

    const dim3 blk(256);

    // conversions (bf16x2 split of inputs/weights)
    CvtArgs ca = {{
        { z,      z2,   1024 * 256, 8 },
        { w_d_w,  wd2,  256 * 256,  8 },
        { w_c_w,  wc2,  256 * 256,  8 },
        { z2h1_w, z12,  256 * 256,  8 },
        { z2h2_w, z22,  256 * 256,  8 },
        { ga_wh,  gaW2, 768 * 256,  8 },
        { gs_wh,  gsW2, 768 * 256,  8 },
        { gs_wx,  gsX2, 768 * 32,   5 },
    }};
    cvt_bf16x2<<<dim3(64, 8), blk, 0, stream>>>(ca);

    // init: hac = z@z2h1^T+b ; H(root) = z@z2h2^T+b ; root pred+softmax
    mfma_gemm<<<dim3(8, 2), blk, 0, stream>>>(z2, z12, z2h1_b, hacF0, hac20, 256, 1, 0);
    mfma_gemm<<<dim3(8, 2), blk, 0, stream>>>(z2, z22, z2h2_b, nullptr, H2a, 256, 1, 0);
    pred_softmax<<<dim3(128), blk, 0, stream>>>(H2a, h2o_w, h2o_b, out, SP2a, 0, 1, 0);

    unsigned short* cur2 = H2a;  unsigned short* nxt2 = H2b;
    unsigned short* spc  = SP2a; unsigned short* spn  = SP2b;
    float* hf = hacF0;  float* hn = hacF1;
    unsigned short* hf2 = hac20; unsigned short* hn2 = hac21;

    for (int l = 0; l < DEPTHC - 1; ++l) {
        const int n = 1 << l;
        const int M = n * Bdim;

        // first children: H' = lin_d(H) -> slots 2p (bf16x2 only)
        mfma_gemm<<<dim3(M / 128, 2), blk, 0, stream>>>(cur2, wd2, w_d_b, nullptr, nxt2, 256, 2, 0);
        // pred + softmax of first children
        pred_softmax<<<dim3(M / 8), blk, 0, stream>>>(nxt2, h2o_w, h2o_b, out, spn, l + 1, 2, 0);
        // shared ancestral gate h-part: GhA = hac @ ga_wh^T + ga_bh  [1024 x 768]
        mfma_gemm<<<dim3(8, 6), blk, 0, stream>>>(hf2, gaW2, ga_bh, GhA, nullptr, 768, 1, 0);
        // ancestral GRU: Ap = gru_a(sp_parent, hac)
        gru_a_kernel<<<dim3(M / 16), blk, 0, stream>>>(spc, GhA, ga_wx, ga_bx, hf, Ap);
        // fraternal GRU on first children + combine -> hidden2 (bf16x2) in Ap2
        gru_s_fused<<<dim3(M / 128, 4), blk, 0, stream>>>(nxt2, spn, gsW2, gsX2, gs_bx, gs_bh, Ap, Ap2);
        // second children: H'' = lin_d(hidden2) -> slots 2p+1
        mfma_gemm<<<dim3(M / 128, 2), blk, 0, stream>>>(Ap2, wd2, w_d_b, nullptr, nxt2, 256, 2, 1);
        // pred + softmax of second children
        pred_softmax<<<dim3(M / 8), blk, 0, stream>>>(nxt2, h2o_w, h2o_b, out, spn, l + 1, 2, 1);
        // next-level shared ancestral hidden: hac' = lin_c(hac)
        mfma_gemm<<<dim3(8, 2), blk, 0, stream>>>(hf2, wc2, w_c_b, hn, hn2, 256, 1, 0);

        // swap ping-pong buffers
        unsigned short* t2;
        t2 = cur2; cur2 = nxt2; nxt2 = t2;
        t2 = spc;  spc  = spn;  spn  = t2;
        float* tf = hf; hf = hn; hn = tf;
        t2 = hf2; hf2 = hn2; hn2 = t2;
    }
}